// Round 1
// baseline (232.824 us; speedup 1.0000x reference)
//
#include <hip/hip_runtime.h>

typedef __bf16 bf16_t;
typedef __bf16 bf16x4 __attribute__((ext_vector_type(4)));
typedef __bf16 bf16x8 __attribute__((ext_vector_type(8)));
typedef float f32x4 __attribute__((ext_vector_type(4)));

#define MFMA(a, b, c) __builtin_amdgcn_mfma_f32_16x16x32_bf16(a, b, c, 0, 0, 0)

// ---------------- f32 -> bf16 convert (x4 vectorized) ----------------
__global__ void cvt_kernel(const float* __restrict__ src, bf16_t* __restrict__ dst, int n4) {
  int i = blockIdx.x * blockDim.x + threadIdx.x;
  if (i >= n4) return;
  const float4 v = reinterpret_cast<const float4*>(src)[i];
  bf16x4 o = { (bf16_t)v.x, (bf16_t)v.y, (bf16_t)v.z, (bf16_t)v.w };
  reinterpret_cast<bf16x4*>(dst)[i] = o;
}

// ---------------- QKV projection GEMM ----------------
// Y[s,j] = sum_k X[s,k] * W[j,k] + bias[j]   (torch Linear, W row-major [out,in])
// Tile 128x128, BK=32, 4 waves (2x2), each wave 64x64 = 4x4 frags of 16x16.
// Epilogue: z=0 -> Q [B,H,S,64]; z=1 -> K [B,H,S,64]; z=2 -> V transposed [B,H,64,S].
#define LDT 40  // padded LDS row (32 + 8) in bf16 elements

__global__ __launch_bounds__(256)
void qkv_gemm(const bf16_t* __restrict__ X, const bf16_t* __restrict__ Wb,
              const float* __restrict__ bq, const float* __restrict__ bk,
              const float* __restrict__ bv,
              bf16_t* __restrict__ Qo, bf16_t* __restrict__ Ko, bf16_t* __restrict__ Vo)
{
  __shared__ __align__(16) bf16_t sA[128 * LDT];
  __shared__ __align__(16) bf16_t sB[128 * LDT];

  const int tid = threadIdx.x;
  const int lane = tid & 63, w = tid >> 6;
  const int wr = w >> 1, wc = w & 1;
  const int lq = lane & 15, lg = lane >> 4;
  const int m0 = blockIdx.x * 128;
  const int n0 = blockIdx.y * 128;
  const int z  = blockIdx.z;

  const bf16_t* W = Wb + z * 589824;
  const float* bias = (z == 0) ? bq : (z == 1) ? bk : bv;

  // staging: thread t loads row r=t>>1, col-half (t&1)*16, two bf16x8 each
  const int sr = tid >> 1, sc = (tid & 1) * 16;
  const bf16_t* gA = X + (m0 + sr) * 768 + sc;
  const bf16_t* gB = W + (n0 + sr) * 768 + sc;

  f32x4 acc[4][4] = {};

  bf16x8 ra0 = *(const bf16x8*)(gA);
  bf16x8 ra1 = *(const bf16x8*)(gA + 8);
  bf16x8 rb0 = *(const bf16x8*)(gB);
  bf16x8 rb1 = *(const bf16x8*)(gB + 8);

  const int arow = wr * 64, brow = wc * 64;

  for (int kt = 0; kt < 24; ++kt) {
    __syncthreads();
    *(bf16x8*)&sA[sr * LDT + sc]     = ra0;
    *(bf16x8*)&sA[sr * LDT + sc + 8] = ra1;
    *(bf16x8*)&sB[sr * LDT + sc]     = rb0;
    *(bf16x8*)&sB[sr * LDT + sc + 8] = rb1;
    __syncthreads();
    if (kt < 23) {
      const bf16_t* pA = gA + (kt + 1) * 32;
      const bf16_t* pB = gB + (kt + 1) * 32;
      ra0 = *(const bf16x8*)(pA);
      ra1 = *(const bf16x8*)(pA + 8);
      rb0 = *(const bf16x8*)(pB);
      rb1 = *(const bf16x8*)(pB + 8);
    }
    bf16x8 af[4], bfr[4];
    const int ko = lg * 8;
#pragma unroll
    for (int mf = 0; mf < 4; ++mf)
      af[mf] = *(const bf16x8*)&sA[(arow + mf * 16 + lq) * LDT + ko];
#pragma unroll
    for (int nf = 0; nf < 4; ++nf)
      bfr[nf] = *(const bf16x8*)&sB[(brow + nf * 16 + lq) * LDT + ko];
#pragma unroll
    for (int mf = 0; mf < 4; ++mf)
#pragma unroll
      for (int nf = 0; nf < 4; ++nf)
        acc[mf][nf] = MFMA(af[mf], bfr[nf], acc[mf][nf]);
  }

  // epilogue: D[row=(lg*4+jr)+mf*16][col=lq+nf*16] (verified gfx950 C/D layout)
#pragma unroll
  for (int nf = 0; nf < 4; ++nf) {
    const int j = n0 + brow + nf * 16 + lq;
    const float bval = bias[j];
    const int h = j >> 6, dd = j & 63;
#pragma unroll
    for (int mf = 0; mf < 4; ++mf) {
#pragma unroll
      for (int jr = 0; jr < 4; ++jr) {
        const int s = m0 + arow + mf * 16 + lg * 4 + jr;
        const int b = s >> 10, sq = s & 1023;
        const bf16_t o = (bf16_t)(acc[mf][nf][jr] + bval);
        if (z == 2)      Vo[((b * 12 + h) * 64 + dd) * 1024 + sq] = o;  // V^T
        else if (z == 0) Qo[((b * 12 + h) * 1024 + sq) * 64 + dd] = o;
        else             Ko[((b * 12 + h) * 1024 + sq) * 64 + dd] = o;
      }
    }
  }
}

// ---------------- fused attention ----------------
// Block: (q-block of 32 rows) x (one b,h). 256 threads = 4 waves.
// Pass 1: P^T[t,q] = K·Q^T via swapped MFMA, p = exp2(acc * log2e/sqrt(768))
//         stored unnormalized bf16 in LDS, row-sums reduced per q.
// Then:   coalesced normalized fp32 A write; PV from LDS P with V^T global frags.
__global__ __launch_bounds__(256)
void attn_kernel(const bf16_t* __restrict__ Q, const bf16_t* __restrict__ K,
                 const bf16_t* __restrict__ V, float* __restrict__ out,
                 float* __restrict__ Aout)
{
  __shared__ __align__(16) bf16_t Pl[32 * 1032];  // 32 q-rows x 1024 t (+8 pad)
  __shared__ __align__(16) bf16_t Ql[32 * 72];    // 32 q-rows x 64 d (+8 pad)
  __shared__ float red[4][32];
  __shared__ float inv_s[32];

  const int tid = threadIdx.x, lane = tid & 63, w = tid >> 6;
  const int lq = lane & 15, lg = lane >> 4;
  const int bh = blockIdx.y, q0 = blockIdx.x * 32;

  const bf16_t* Qp = Q + (bh * 1024 + q0) * 64;
  const bf16_t* Kp = K + bh * 1024 * 64;
  const bf16_t* Vt = V + bh * 64 * 1024;

  {  // load Q block 32x64
    const int q = tid >> 3, du = (tid & 7) * 8;
    *(bf16x8*)&Ql[q * 72 + du] = *(const bf16x8*)(Qp + q * 64 + du);
  }
  __syncthreads();

  const float CEXP = 1.4426950408889634f / 27.712812921102035f;  // log2(e)/sqrt(768)

  bf16x8 bqf[2][2];
#pragma unroll
  for (int dh = 0; dh < 2; ++dh)
#pragma unroll
    for (int qf = 0; qf < 2; ++qf)
      bqf[dh][qf] = *(const bf16x8*)&Ql[(qf * 16 + lq) * 72 + dh * 32 + lg * 8];

  float psum0 = 0.f, psum1 = 0.f;

  for (int i = 0; i < 4; ++i) {
    const int t0 = (w + i * 4) * 64;
    bf16x8 af[4][2];
#pragma unroll
    for (int mf = 0; mf < 4; ++mf) {
      const bf16_t* kp = Kp + (t0 + mf * 16 + lq) * 64 + lg * 8;
      af[mf][0] = *(const bf16x8*)(kp);
      af[mf][1] = *(const bf16x8*)(kp + 32);
    }
#pragma unroll
    for (int mf = 0; mf < 4; ++mf) {
#pragma unroll
      for (int qf = 0; qf < 2; ++qf) {
        f32x4 acc = {};
        acc = MFMA(af[mf][0], bqf[0][qf], acc);
        acc = MFMA(af[mf][1], bqf[1][qf], acc);
        float p0 = exp2f(acc[0] * CEXP);
        float p1 = exp2f(acc[1] * CEXP);
        float p2 = exp2f(acc[2] * CEXP);
        float p3 = exp2f(acc[3] * CEXP);
        if (qf == 0) psum0 += p0 + p1 + p2 + p3;
        else         psum1 += p0 + p1 + p2 + p3;
        bf16x4 pv = { (bf16_t)p0, (bf16_t)p1, (bf16_t)p2, (bf16_t)p3 };
        const int q = qf * 16 + lq;
        const int tt = t0 + mf * 16 + lg * 4;
        *(bf16x4*)&Pl[q * 1032 + tt] = pv;
      }
    }
  }

  psum0 += __shfl_xor(psum0, 16); psum0 += __shfl_xor(psum0, 32);
  psum1 += __shfl_xor(psum1, 16); psum1 += __shfl_xor(psum1, 32);
  if (lane < 16) { red[w][lane] = psum0; red[w][16 + lane] = psum1; }
  __syncthreads();
  if (tid < 32)
    inv_s[tid] = 1.0f / (red[0][tid] + red[1][tid] + red[2][tid] + red[3][tid]);
  __syncthreads();

  // ---- normalized A write (coalesced: 8 threads per q-row) ----
  {
    const int q = tid >> 3, c = tid & 7;
    const float inv = inv_s[q];
    float* Ap = Aout + ((size_t)bh * 1024 + q0 + q) * 1024;
#pragma unroll
    for (int i = 0; i < 16; ++i) {
      const int toff = i * 64 + c * 8;
      bf16x8 pv = *(const bf16x8*)&Pl[q * 1032 + toff];
      float4 o0 = make_float4((float)pv[0] * inv, (float)pv[1] * inv,
                              (float)pv[2] * inv, (float)pv[3] * inv);
      float4 o1 = make_float4((float)pv[4] * inv, (float)pv[5] * inv,
                              (float)pv[6] * inv, (float)pv[7] * inv);
      *(float4*)(Ap + toff)     = o0;
      *(float4*)(Ap + toff + 4) = o1;
    }
  }

  // ---- PV: out[q, d] = inv_s[q] * sum_t P[q,t] V[t,d]; wave w owns d-range w*16 ----
  f32x4 oacc[2] = {};
  for (int ks = 0; ks < 32; ++ks) {
    const int kc = ks * 32;
    bf16x8 vb = *(const bf16x8*)(Vt + (w * 16 + lq) * 1024 + kc + lg * 8);
#pragma unroll
    for (int mf = 0; mf < 2; ++mf) {
      bf16x8 pa = *(const bf16x8*)&Pl[(mf * 16 + lq) * 1032 + kc + lg * 8];
      oacc[mf] = MFMA(pa, vb, oacc[mf]);
    }
  }

  const int b = bh / 12, h = bh % 12;
#pragma unroll
  for (int mf = 0; mf < 2; ++mf) {
#pragma unroll
    for (int jr = 0; jr < 4; ++jr) {
      const int q = mf * 16 + lg * 4 + jr;
      out[((b * 1024) + q0 + q) * 768 + h * 64 + w * 16 + lq] = oacc[mf][jr] * inv_s[q];
    }
  }
}

extern "C" void kernel_launch(void* const* d_in, const int* in_sizes, int n_in,
                              void* d_out, int out_size, void* d_ws, size_t ws_size,
                              hipStream_t stream) {
  (void)in_sizes; (void)n_in; (void)out_size; (void)ws_size;
  const float* x  = (const float*)d_in[0];
  const float* Wq = (const float*)d_in[1];
  const float* bq = (const float*)d_in[2];
  const float* Wk = (const float*)d_in[3];
  const float* bk = (const float*)d_in[4];
  const float* Wv = (const float*)d_in[5];
  const float* bv = (const float*)d_in[6];

  float* out  = (float*)d_out;
  float* Aout = out + 6291456;  // out is [8,1024,768]; A follows

  // workspace layout (bf16 elements): x_bf | wq|wk|wv | q | k | v^T  (~54 MB)
  bf16_t* ws   = (bf16_t*)d_ws;
  bf16_t* x_bf = ws;
  bf16_t* w_bf = ws + 6291456;
  bf16_t* q_ws = ws + 8060928;
  bf16_t* k_ws = ws + 14352384;
  bf16_t* v_ws = ws + 20643840;

  cvt_kernel<<<6144, 256, 0, stream>>>(x,  x_bf,            1572864);
  cvt_kernel<<<576,  256, 0, stream>>>(Wq, w_bf,            147456);
  cvt_kernel<<<576,  256, 0, stream>>>(Wk, w_bf + 589824,   147456);
  cvt_kernel<<<576,  256, 0, stream>>>(Wv, w_bf + 1179648,  147456);

  qkv_gemm<<<dim3(64, 6, 3), 256, 0, stream>>>(x_bf, w_bf, bq, bk, bv, q_ws, k_ws, v_ws);
  attn_kernel<<<dim3(32, 96), 256, 0, stream>>>(q_ws, k_ws, v_ws, out, Aout);
}